// Round 1
// baseline (157.472 us; speedup 1.0000x reference)
//
#include <hip/hip_runtime.h>

#define NTYPES 11
#define BLOCK  256
#define ITEMS  8
#define CHUNK  (BLOCK * ITEMS)   // 2048 atoms per block

// ---------------------------------------------------------------------------
// Kernel 1: per-block per-type histogram.
// bc[t*Bp + b] = number of atoms of type t in block b's chunk (u16, <=2048).
// ---------------------------------------------------------------------------
__global__ __launch_bounds__(BLOCK) void hist_kernel(
    const int* __restrict__ types, int N, int Bp,
    unsigned short* __restrict__ bc) {
  __shared__ int shCnt[NTYPES];
  const int tid = threadIdx.x;
  const int b = blockIdx.x;
  if (tid < NTYPES) shCnt[tid] = 0;
  __syncthreads();

  const int run = b * CHUNK + tid * ITEMS;
  int cnt[NTYPES];
#pragma unroll
  for (int t = 0; t < NTYPES; ++t) cnt[t] = 0;

  if (run < N) {
    const int4* p = (const int4*)(types + run);
    int4 a0 = p[0], a1 = p[1];
    int ty[ITEMS] = {a0.x, a0.y, a0.z, a0.w, a1.x, a1.y, a1.z, a1.w};
#pragma unroll
    for (int k = 0; k < ITEMS; ++k) {
#pragma unroll
      for (int t = 0; t < NTYPES; ++t) cnt[t] += (ty[k] == t) ? 1 : 0;
    }
  }

  const int lane = tid & 63;
#pragma unroll
  for (int t = 0; t < NTYPES; ++t) {
    int v = cnt[t];
    for (int o = 32; o >= 1; o >>= 1) v += __shfl_down(v, o);
    if (lane == 0) atomicAdd(&shCnt[t], v);
  }
  __syncthreads();
  if (tid < NTYPES) bc[tid * Bp + b] = (unsigned short)shCnt[tid];
}

// ---------------------------------------------------------------------------
// Kernel 2: fused scan + stable scatter.
// Phase A: each block redundantly computes, from the u16 block counts
//          (L2-resident, 43 KB), its own per-type exclusive prefix AND the
//          global per-type totals/offsets. Replaces the single-block scan
//          kernel (which left 255 CUs idle) with ~3 us of L2 traffic that
//          overlaps the coords HBM stream.
// Phase B: stable in-block rank, scatter coords into type-sorted LDS.
// Phase C: copy-out over FLAT float indices -> stride-1 LDS reads and fully
//          contiguous global store bursts (was stride-3 x 3 passes).
// ---------------------------------------------------------------------------
__global__ __launch_bounds__(BLOCK) void scatter_kernel(
    const float* __restrict__ coords, const int* __restrict__ types,
    const unsigned short* __restrict__ bc, int N, int B, int Bp,
    float* __restrict__ out) {
  __shared__ float shC[CHUNK * 3];      // 24 KB type-sorted coords
  __shared__ int red[NTYPES][2][4];     // per-wave {pre, tot} partials
  __shared__ int shPre[NTYPES];         // sum of counts in blocks < b
  __shared__ int shTot[NTYPES];         // global per-type totals
  __shared__ int shGOff[NTYPES];        // global per-type offsets
  __shared__ int wtot[NTYPES][4];       // per-wave inclusive totals
  __shared__ int shOff[NTYPES + 1];     // local bucket offsets (exclusive)
  __shared__ int shDelta[NTYPES];       // 3*(globalBase[t] - shOff[t])

  const int tid = threadIdx.x;
  const int b = blockIdx.x;
  const int lane = tid & 63;
  const int wave = tid >> 6;
  const int run = b * CHUNK + tid * ITEMS;
  const bool active = (run < N);

  // ---- load this thread's atoms (issued early; latency hides under phase A)
  int ty[ITEMS];
#pragma unroll
  for (int k = 0; k < ITEMS; ++k) ty[k] = -1;
  float c[ITEMS * 3];
  if (active) {
    const int4* p = (const int4*)(types + run);
    int4 a0 = p[0], a1 = p[1];
    int tt[ITEMS] = {a0.x, a0.y, a0.z, a0.w, a1.x, a1.y, a1.z, a1.w};
#pragma unroll
    for (int k = 0; k < ITEMS; ++k) ty[k] = tt[k];
    const float4* cp = (const float4*)(coords + (size_t)run * 3);
#pragma unroll
    for (int q = 0; q < (ITEMS * 3) / 4; ++q) {
      float4 v = cp[q];
      c[4 * q + 0] = v.x;
      c[4 * q + 1] = v.y;
      c[4 * q + 2] = v.z;
      c[4 * q + 3] = v.w;
    }
  }

  // ---- Phase A: redundant prefix/total over u16 block counts (L2-hot).
  const unsigned int* bc32 = (const unsigned int*)bc;
  const int halfB = Bp >> 1;
  int preAcc[NTYPES], totAcc[NTYPES];
#pragma unroll
  for (int t = 0; t < NTYPES; ++t) {
    preAcc[t] = 0;
    totAcc[t] = 0;
  }
  for (int i = tid; i < halfB; i += BLOCK) {
    const int u0 = 2 * i;
    const int u1 = 2 * i + 1;
#pragma unroll
    for (int t = 0; t < NTYPES; ++t) {
      const unsigned int v = bc32[t * halfB + i];
      int v0 = (int)(v & 0xFFFFu);
      int v1 = (int)(v >> 16);
      v1 = (u1 < B) ? v1 : 0;  // mask pad element (ws is poisoned)
      totAcc[t] += v0 + v1;
      preAcc[t] += ((u0 < b) ? v0 : 0) + ((u1 < b) ? v1 : 0);
    }
  }
#pragma unroll
  for (int t = 0; t < NTYPES; ++t) {
    int p = preAcc[t], q = totAcc[t];
    for (int o = 32; o >= 1; o >>= 1) {
      p += __shfl_down(p, o);
      q += __shfl_down(q, o);
    }
    if (lane == 0) {
      red[t][0][wave] = p;
      red[t][1][wave] = q;
    }
  }
  __syncthreads();
  if (tid < NTYPES) {
    shPre[tid] = red[tid][0][0] + red[tid][0][1] + red[tid][0][2] + red[tid][0][3];
    shTot[tid] = red[tid][1][0] + red[tid][1][1] + red[tid][1][2] + red[tid][1][3];
  }
  __syncthreads();
  if (tid == 0) {
    int off = 0;
#pragma unroll
    for (int t = 0; t < NTYPES; ++t) {
      shGOff[t] = off;
      off += shTot[t];
    }
  }
  __syncthreads();

  // counts/offsets tail (as floats) — block 0 only
  if (b == 0 && tid == 0) {
    float* tail = out + (size_t)3 * N;
#pragma unroll
    for (int t = 0; t < NTYPES; ++t) {
      tail[t] = (float)shTot[t];
      tail[NTYPES + t] = (float)shGOff[t];
    }
  }

  // ---- Phase B: stable in-block ranks.
  int cnt[NTYPES];
#pragma unroll
  for (int t = 0; t < NTYPES; ++t) cnt[t] = 0;
#pragma unroll
  for (int k = 0; k < ITEMS; ++k) {
#pragma unroll
    for (int t = 0; t < NTYPES; ++t) cnt[t] += (ty[k] == t) ? 1 : 0;
  }

  int rank[NTYPES];
#pragma unroll
  for (int t = 0; t < NTYPES; ++t) {
    int incl = cnt[t];
#pragma unroll
    for (int o = 1; o < 64; o <<= 1) {
      int v = __shfl_up(incl, o);
      if (lane >= o) incl += v;
    }
    if (lane == 63) wtot[t][wave] = incl;
    rank[t] = incl - cnt[t];  // exclusive within wave
  }
  __syncthreads();

  if (tid < NTYPES) {
    int loc = 0;
    for (int u = 0; u < tid; ++u)
      loc += wtot[u][0] + wtot[u][1] + wtot[u][2] + wtot[u][3];
    shOff[tid] = loc;
    shDelta[tid] = 3 * (shGOff[tid] + shPre[tid] - loc);
    if (tid == NTYPES - 1) {
      shOff[NTYPES] =
          loc + wtot[tid][0] + wtot[tid][1] + wtot[tid][2] + wtot[tid][3];
    }
  }
  __syncthreads();

  // Finalize local ranks: bucket base + wave base + lane-exclusive.
#pragma unroll
  for (int t = 0; t < NTYPES; ++t) {
    int wb = 0;
#pragma unroll
    for (int w = 0; w < 3; ++w) wb += (w < wave) ? wtot[t][w] : 0;
    rank[t] += wb + shOff[t];
  }

  // Scatter coords into type-sorted LDS buffer.
  if (active) {
#pragma unroll
    for (int k = 0; k < ITEMS; ++k) {
      const int t0 = ty[k];
      int slot = 0;
#pragma unroll
      for (int t = 0; t < NTYPES; ++t) {
        if (t0 == t) {
          slot = rank[t];
          rank[t] += 1;
        }
      }
      shC[3 * slot + 0] = c[3 * k + 0];
      shC[3 * slot + 1] = c[3 * k + 1];
      shC[3 * slot + 2] = c[3 * k + 2];
    }
  }
  __syncthreads();

  // ---- Phase C: copy-out over flat float indices.
  // Slot s of type t -> global float index 3*s + shDelta[t]; boundaries in
  // float space are 3*shOff[t], so the per-element segment search works on
  // flat indices directly. Stride-1 LDS reads, contiguous global bursts.
  const int total3 = 3 * shOff[NTYPES];
  int offr3[NTYPES];
  int dlt[NTYPES];
#pragma unroll
  for (int t = 0; t < NTYPES; ++t) {
    offr3[t] = 3 * shOff[t];
    dlt[t] = shDelta[t];
  }
#pragma unroll
  for (int k = 0; k < ITEMS * 3; ++k) {
    const int j = k * BLOCK + tid;
    if (j < total3) {
      int d = dlt[0];
#pragma unroll
      for (int t = 1; t < NTYPES; ++t) d = (j >= offr3[t]) ? dlt[t] : d;
      out[j + d] = shC[j];
    }
  }
}

extern "C" void kernel_launch(void* const* d_in, const int* in_sizes, int n_in,
                              void* d_out, int out_size, void* d_ws,
                              size_t ws_size, hipStream_t stream) {
  const float* coords = (const float*)d_in[0];
  const int* types = (const int*)d_in[1];
  const int N = in_sizes[1];              // 4,000,000 atoms
  const int B = (N + CHUNK - 1) / CHUNK;  // 1954 blocks
  const int Bp = (B + 1) & ~1;            // even-padded for u32 paired loads

  unsigned short* bc = (unsigned short*)d_ws;  // [NTYPES * Bp] u16
  float* out = (float*)d_out;

  hist_kernel<<<B, BLOCK, 0, stream>>>(types, N, Bp, bc);
  scatter_kernel<<<B, BLOCK, 0, stream>>>(coords, types, bc, N, B, Bp, out);
}

// Round 4
// 142.347 us; speedup vs baseline: 1.1063x; 1.1063x over previous
//
#include <hip/hip_runtime.h>

#define NTYPES 11
#define BLOCK  256
#define ITEMS  8
#define CHUNK  (BLOCK * ITEMS)   // 2048 atoms per block
#define PERMAX 32                // per-lane scan elements (B <= 2048)
#define SCATTER_GRID 1536        // 6 blocks/CU (24 KB LDS) x 256 CU

// ---------------------------------------------------------------------------
// Kernel 1: per-block per-type histogram.
// bc[t*B + b] = number of atoms of type t in block b's chunk.
// ---------------------------------------------------------------------------
__global__ __launch_bounds__(BLOCK) void hist_kernel(
    const int* __restrict__ types, int N, int B, int* __restrict__ bc) {
  __shared__ int shCnt[NTYPES];
  const int tid = threadIdx.x;
  const int b = blockIdx.x;
  if (tid < NTYPES) shCnt[tid] = 0;
  __syncthreads();

  const int run = b * CHUNK + tid * ITEMS;
  int cnt[NTYPES];
#pragma unroll
  for (int t = 0; t < NTYPES; ++t) cnt[t] = 0;

  if (run < N) {
    const int4* p = (const int4*)(types + run);
    int4 a0 = p[0], a1 = p[1];
    int ty[ITEMS] = {a0.x, a0.y, a0.z, a0.w, a1.x, a1.y, a1.z, a1.w};
#pragma unroll
    for (int k = 0; k < ITEMS; ++k) {
#pragma unroll
      for (int t = 0; t < NTYPES; ++t) cnt[t] += (ty[k] == t) ? 1 : 0;
    }
  }

  const int lane = tid & 63;
#pragma unroll
  for (int t = 0; t < NTYPES; ++t) {
    int v = cnt[t];
    for (int o = 32; o >= 1; o >>= 1) v += __shfl_down(v, o);
    if (lane == 0) atomicAdd(&shCnt[t], v);
  }
  __syncthreads();
  if (tid < NTYPES) bc[tid * B + b] = shCnt[tid];
}

// ---------------------------------------------------------------------------
// Kernel 2: one block, 11 waves; wave t scans type t's block-counts.
// Lane-serial decomposition: lane l owns counts [l*per, l*per+per). One
// 6-stage shfl scan of the per-lane sums replaces the old 31-chunk serial
// chain (~217 dependent DS ops -> ~40). scanOut written directly (the whole
// writeback is only ~21.5K dwords -- volume is trivial for one block).
// ---------------------------------------------------------------------------
__global__ __launch_bounds__(NTYPES * 64) void scan_kernel(
    const int* __restrict__ bc, int B, int* __restrict__ scanOut,
    int* __restrict__ offs, float* __restrict__ outTail) {
  __shared__ int totals[NTYPES];
  const int lane = threadIdx.x & 63;
  const int t = threadIdx.x >> 6;
  const int per = (B + 63) >> 6;  // 31 for B=1954
  const int base = lane * per;

  int x[PERMAX];
#pragma unroll
  for (int j = 0; j < PERMAX; ++j) {
    const int idx = base + j;
    x[j] = (j < per && idx < B) ? bc[t * B + idx] : 0;
  }
  int s = 0;
#pragma unroll
  for (int j = 0; j < PERMAX; ++j) s += x[j];

  int incl = s;
#pragma unroll
  for (int o = 1; o < 64; o <<= 1) {
    int v = __shfl_up(incl, o);
    if (lane >= o) incl += v;
  }
  int run = incl - s;  // exclusive prefix of this lane's first element
  const int total = __shfl(incl, 63);

#pragma unroll
  for (int j = 0; j < PERMAX; ++j) {
    const int idx = base + j;
    if (j < per && idx < B) scanOut[t * B + idx] = run;
    run += x[j];
  }
  if (lane == 0) totals[t] = total;
  __syncthreads();

  if (threadIdx.x == 0) {
    int off = 0;
    for (int u = 0; u < NTYPES; ++u) {
      const int c = totals[u];
      offs[u] = off;
      outTail[u] = (float)c;            // counts (as float values)
      outTail[NTYPES + u] = (float)off; // offsets (as float values)
      off += c;
    }
  }
}

// ---------------------------------------------------------------------------
// Kernel 3: stable scatter with LDS bucket staging.
// Persistent grid (1536 = exact residency): each block loops over chunks,
// eliminating the 418-block low-occupancy tail wave of the 1954-block grid.
// Rank phase packs 2 types per u32 (in-wave inclusive sums <= 512 < 2^16):
// 6 packed int scans instead of 11 (66 -> 36 DS ops per wave), using only
// the 32-bit shuffle path the verified baseline already exercised.
// ---------------------------------------------------------------------------
__global__ __launch_bounds__(BLOCK) void scatter_kernel(
    const float* __restrict__ coords, const int* __restrict__ types,
    const int* __restrict__ scanOut, const int* __restrict__ offs, int N,
    int B, float* __restrict__ out) {
  __shared__ float shC[CHUNK * 3];      // 24 KB type-sorted coords
  __shared__ int wtot[NTYPES][4];       // per-wave inclusive totals
  __shared__ int shOff[NTYPES + 1];     // local bucket offsets (exclusive)
  __shared__ int shDelta[NTYPES];       // 3*(globalBase[t] - shOff[t])

  const int tid = threadIdx.x;
  const int lane = tid & 63;
  const int wave = tid >> 6;

  for (int b = blockIdx.x; b < B; b += gridDim.x) {
    __syncthreads();  // guard LDS reuse across chunk iterations

    const int run = b * CHUNK + tid * ITEMS;
    const bool active = (run < N);

    int ty[ITEMS];
    int cnt[NTYPES];
#pragma unroll
    for (int t = 0; t < NTYPES; ++t) cnt[t] = 0;
#pragma unroll
    for (int k = 0; k < ITEMS; ++k) ty[k] = -1;

    float c[ITEMS * 3];
    if (active) {
      const int4* p = (const int4*)(types + run);
      int4 a0 = p[0], a1 = p[1];
      int tt[ITEMS] = {a0.x, a0.y, a0.z, a0.w, a1.x, a1.y, a1.z, a1.w};
#pragma unroll
      for (int k = 0; k < ITEMS; ++k) ty[k] = tt[k];
      const float4* cp = (const float4*)(coords + (size_t)run * 3);
#pragma unroll
      for (int q = 0; q < (ITEMS * 3) / 4; ++q) {
        float4 v = cp[q];
        c[4 * q + 0] = v.x;
        c[4 * q + 1] = v.y;
        c[4 * q + 2] = v.z;
        c[4 * q + 3] = v.w;
      }
#pragma unroll
      for (int k = 0; k < ITEMS; ++k) {
#pragma unroll
        for (int t = 0; t < NTYPES; ++t) cnt[t] += (ty[k] == t) ? 1 : 0;
      }
    }

    // Wave-level stable exclusive scan, 2 types packed per int.
    int pk[6];
#pragma unroll
    for (int q = 0; q < 5; ++q) pk[q] = cnt[2 * q] | (cnt[2 * q + 1] << 16);
    pk[5] = cnt[10];
#pragma unroll
    for (int o = 1; o < 64; o <<= 1) {
      int v0 = __shfl_up(pk[0], o);
      int v1 = __shfl_up(pk[1], o);
      int v2 = __shfl_up(pk[2], o);
      int v3 = __shfl_up(pk[3], o);
      int v4 = __shfl_up(pk[4], o);
      int v5 = __shfl_up(pk[5], o);
      if (lane >= o) {
        pk[0] += v0;
        pk[1] += v1;
        pk[2] += v2;
        pk[3] += v3;
        pk[4] += v4;
        pk[5] += v5;
      }
    }
    int rank[NTYPES];
#pragma unroll
    for (int t = 0; t < NTYPES; ++t) {
      const int incl = (pk[t >> 1] >> ((t & 1) * 16)) & 0xFFFF;
      if (lane == 63) wtot[t][wave] = incl;
      rank[t] = incl - cnt[t];  // exclusive within wave
    }
    __syncthreads();

    // Local bucket offsets + global deltas (threads 0..NTYPES-1).
    if (tid < NTYPES) {
      int loc = 0;
      for (int u = 0; u < tid; ++u)
        loc += wtot[u][0] + wtot[u][1] + wtot[u][2] + wtot[u][3];
      shOff[tid] = loc;
      shDelta[tid] = 3 * (offs[tid] + scanOut[tid * B + b] - loc);
      if (tid == NTYPES - 1) {
        shOff[NTYPES] =
            loc + wtot[tid][0] + wtot[tid][1] + wtot[tid][2] + wtot[tid][3];
      }
    }
    __syncthreads();

    // Finalize local ranks: bucket base + wave base + lane-exclusive.
#pragma unroll
    for (int t = 0; t < NTYPES; ++t) {
      int wb = 0;
#pragma unroll
      for (int w = 0; w < 3; ++w) wb += (w < wave) ? wtot[t][w] : 0;
      rank[t] += wb + shOff[t];
    }

    // Scatter coords into type-sorted LDS buffer.
    if (active) {
#pragma unroll
      for (int k = 0; k < ITEMS; ++k) {
        const int t0 = ty[k];
        int slot = 0;
#pragma unroll
        for (int t = 0; t < NTYPES; ++t) {
          if (t0 == t) {
            slot = rank[t];
            rank[t] += 1;
          }
        }
        shC[3 * slot + 0] = c[3 * k + 0];
        shC[3 * slot + 1] = c[3 * k + 1];
        shC[3 * slot + 2] = c[3 * k + 2];
      }
    }
    __syncthreads();

    // Coalesced copy-out: slot s -> global float index 3*s + delta3[type(s)].
    const int total = shOff[NTYPES];
    int offr[NTYPES];
    int dlt[NTYPES];
#pragma unroll
    for (int t = 0; t < NTYPES; ++t) {
      offr[t] = shOff[t];
      dlt[t] = shDelta[t];
    }
#pragma unroll
    for (int k = 0; k < ITEMS; ++k) {
      const int s = k * BLOCK + tid;
      if (s < total) {
        int d = dlt[0];
#pragma unroll
        for (int t = 1; t < NTYPES; ++t) d = (s >= offr[t]) ? dlt[t] : d;
        const int src = 3 * s;
        out[src + d + 0] = shC[src + 0];
        out[src + d + 1] = shC[src + 1];
        out[src + d + 2] = shC[src + 2];
      }
    }
  }
}

extern "C" void kernel_launch(void* const* d_in, const int* in_sizes, int n_in,
                              void* d_out, int out_size, void* d_ws,
                              size_t ws_size, hipStream_t stream) {
  const float* coords = (const float*)d_in[0];
  const int* types = (const int*)d_in[1];
  const int N = in_sizes[1];              // 4,000,000 atoms
  const int B = (N + CHUNK - 1) / CHUNK;  // 1954 blocks

  int* bc = (int*)d_ws;              // [NTYPES * B]
  int* scanOut = bc + NTYPES * B;    // [NTYPES * B]
  int* offs = scanOut + NTYPES * B;  // [NTYPES]
  float* out = (float*)d_out;
  float* outTail = out + (size_t)3 * N;  // counts then offsets, as floats

  const int G = (B < SCATTER_GRID) ? B : SCATTER_GRID;

  hist_kernel<<<B, BLOCK, 0, stream>>>(types, N, B, bc);
  scan_kernel<<<1, NTYPES * 64, 0, stream>>>(bc, B, scanOut, offs, outTail);
  scatter_kernel<<<G, BLOCK, 0, stream>>>(coords, types, scanOut, offs, N, B,
                                          out);
}